// Round 9
// baseline (226.967 us; speedup 1.0000x reference)
//
#include <hip/hip_runtime.h>
#include <stdint.h>
#include <stddef.h>

typedef _Float16 f16_t;
typedef _Float16 f16x4 __attribute__((ext_vector_type(4)));
typedef _Float16 f16x8 __attribute__((ext_vector_type(8)));
typedef float f32x4 __attribute__((ext_vector_type(4)));

#define AS_G __attribute__((address_space(1)))
#define AS_L __attribute__((address_space(3)))

__device__ __forceinline__ void gload_lds16(const void* g, void* l) {
  __builtin_amdgcn_global_load_lds((AS_G void*)g, (AS_L void*)l, 16, 0, 0);
}

#define FENCE() asm volatile("" ::: "memory")
#define BARX()                            \
  do {                                    \
    FENCE();                              \
    __builtin_amdgcn_s_barrier();         \
    FENCE();                              \
  } while (0)
#define VMCNT(n) asm volatile("s_waitcnt vmcnt(" #n ")" ::: "memory")

// ---------------- merged prep + xavg kernel ----------------
// blocks [0,1024): Wo f32->f16 cvt; [1024,2048): Wv transpose+cvt;
// [2048,3072): bconst; [3072,7168): xavg 3-tap (8 rows/block)

__global__ __launch_bounds__(256) void prep_xavg_kernel(
    const float* __restrict__ X, const float* __restrict__ Wo,
    const float* __restrict__ Wv, const float* __restrict__ bv,
    const float* __restrict__ bo, const float* __restrict__ nw, int Kw,
    f16_t* __restrict__ Wo_h, f16_t* __restrict__ WvT, float* __restrict__ bc,
    f16_t* __restrict__ Xavg) {
  __shared__ float smem[32 * 33];
  const int b = blockIdx.x;
  const int t = threadIdx.x;
  if (b >= 3072) {
    const int T = 4096, D = 1024;
    const int base = (b - 3072) * 8;
    const int t0 = base & (T - 1);
    const int col = t * 4;
    const float w0 = nw[0], w1 = nw[1], w2 = nw[2];
    const float* xb = X + (size_t)base * D + col;
    f32x4 va = *(const f32x4*)(xb + (t0 == 0 ? 0 : -D));
    f32x4 vb = *(const f32x4*)(xb);
    f16_t* ob = Xavg + (size_t)base * D + col;
#pragma unroll
    for (int g = 0; g < 8; ++g) {
      f32x4 vc;
      if (t0 + g == T - 1) vc = vb;
      else vc = *(const f32x4*)(xb + (size_t)(g + 1) * D);
      f32x4 y = w0 * va + w1 * vb + w2 * vc;
      f16x4 o;
      o.x = (f16_t)y.x; o.y = (f16_t)y.y; o.z = (f16_t)y.z; o.w = (f16_t)y.w;
      *(f16x4*)(ob + (size_t)g * D) = o;
      va = vb;
      vb = vc;
    }
  } else if (b < 1024) {
    const int i = b * 256 + t;
    f32x4 v = ((const f32x4*)Wo)[i];
    f16x4 o;
    o.x = (f16_t)v.x; o.y = (f16_t)v.y; o.z = (f16_t)v.z; o.w = (f16_t)v.w;
    ((f16x4*)Wo_h)[i] = o;
  } else if (b < 2048) {
    const int i = b - 1024;
    const int bx = i & 31, by = i >> 5;
    const int tx = t & 31, ty = t >> 5;
#pragma unroll
    for (int k = 0; k < 32; k += 8)
      smem[(ty + k) * 33 + tx] = Wv[(size_t)(by * 32 + ty + k) * 1024 + bx * 32 + tx];
    __syncthreads();
#pragma unroll
    for (int k = 0; k < 32; k += 8)
      WvT[(size_t)(bx * 32 + ty + k) * 1024 + by * 32 + tx] = (f16_t)smem[tx * 33 + ty + k];
  } else {
    const int e = b - 2048;
    float sw = 0.f;
    for (int k = 0; k < Kw; ++k) sw += nw[k];
    float p = 0.f;
    for (int d = t; d < 1024; d += 256) p += Wo[(size_t)e * 1024 + d] * bv[d];
    smem[t] = p;
    __syncthreads();
    for (int s = 128; s > 0; s >>= 1) {
      if (t < s) smem[t] += smem[t + s];
      __syncthreads();
    }
    if (t == 0) bc[e] = sw * smem[0] + bo[e];
  }
}

// ---------------- 128^2 GEMM (small 1024^3 WcT GEMM) ----------------

template <typename OutT, bool BIAS>
__global__ __launch_bounds__(256) void gemm_bt_kernel(const f16_t* __restrict__ A,
                                                      const f16_t* __restrict__ Bt,
                                                      OutT* __restrict__ C,
                                                      const float* __restrict__ bias,
                                                      int M, int N, int K) {
  __shared__ __align__(16) f16_t sA[128 * 32];
  __shared__ __align__(16) f16_t sB[128 * 32];
  const int tid = threadIdx.x;
  const int l = tid & 63;
  const int w = tid >> 6;
  const int wr = w >> 1;
  const int wc = w & 1;
  const int nMT = M >> 7;
  const int bid = blockIdx.x;
  const int mt = bid % nMT;
  const int nt = bid / nMT;
  const int m0 = mt << 7;
  const int n0 = nt << 7;

  const int srow = (w << 4) + (l >> 2);
  const int scol = (l & 3) << 3;
  const size_t aoff0 = (size_t)(m0 + srow) * K + scol;
  const size_t boff0 = (size_t)(n0 + srow) * K + scol;
  f16_t* ldsA = sA + (w << 9);
  f16_t* ldsB = sB + (w << 9);

  f32x4 acc[4][4];
#pragma unroll
  for (int i = 0; i < 4; ++i)
#pragma unroll
    for (int j = 0; j < 4; ++j) acc[i][j] = f32x4{0.f, 0.f, 0.f, 0.f};

  const int ka = (l >> 4) << 3;
  const int ar = (wr << 6) + (l & 15);
  const int br = (wc << 6) + (l & 15);

  const int nK = K >> 5;
  for (int kt = 0; kt < nK; ++kt) {
    const int kb = kt << 5;
    gload_lds16(A + aoff0 + kb, ldsA);
    gload_lds16(A + aoff0 + ((size_t)K << 6) + kb, ldsA + 2048);
    gload_lds16(Bt + boff0 + kb, ldsB);
    gload_lds16(Bt + boff0 + ((size_t)K << 6) + kb, ldsB + 2048);
    __syncthreads();
    f16x8 af[4], bfr[4];
#pragma unroll
    for (int m = 0; m < 4; ++m) af[m] = *(const f16x8*)(sA + ((ar + (m << 4)) << 5) + ka);
#pragma unroll
    for (int n = 0; n < 4; ++n) bfr[n] = *(const f16x8*)(sB + ((br + (n << 4)) << 5) + ka);
#pragma unroll
    for (int m = 0; m < 4; ++m)
#pragma unroll
      for (int n = 0; n < 4; ++n)
        acc[m][n] = __builtin_amdgcn_mfma_f32_16x16x32_f16(af[m], bfr[n], acc[m][n], 0, 0, 0);
    __syncthreads();
  }

  const int orow = (l >> 4) << 2;
  const int ocol = l & 15;
#pragma unroll
  for (int n = 0; n < 4; ++n) {
    const int gn = n0 + (wc << 6) + (n << 4) + ocol;
    const float bs = BIAS ? bias[gn] : 0.f;
#pragma unroll
    for (int m = 0; m < 4; ++m) {
      const int gm = m0 + (wr << 6) + (m << 4) + orow;
#pragma unroll
      for (int j = 0; j < 4; ++j) {
        C[(size_t)(gm + j) * N + gn] = (OutT)(acc[m][n][j] + bs);
      }
    }
  }
}

// ---------------- 256^2 GEMM v7: A direct global->reg, B-only LDS ring-4 ----------------
// C[M][N] = A[M][K]*Bt[N][K]^T + bias. 8 waves (2Mx4N), 16x16x32 MFMA, BK=32.
// A-frags (8 x f16x8 per wave per step) loaded straight from global into regs,
// double-buffered across steps (named sets af0/af1 - no runtime indexing).
// The 4 waves sharing wr read identical A lines -> L1 dedup; external A = 16 KB/step/CU.
// B staged via global_load_lds into ring-4 granules (16 KB each, 64 KB LDS total),
// XOR chunk swizzle (proven 0-conflict). Per step issue order: [A(t+1) x8, B(t+2) x2];
// VMCNT(2) at step end drains A(t+1) + B(t+1) (1-step cover), leaves B(t+2) flying.
// Granule hazard: stage B(t+2) targets granule (t+2)&3, last read at step t-2,
// >= 1 barrier before issue. Tails clamped (identical-byte rewrites, uniform counts).

__device__ __forceinline__ void stageB(const f16_t* __restrict__ g, int K,
                                       f16_t* gran, int w, int l) {
#pragma unroll
  for (int i = 0; i < 2; ++i) {
    const int f = i * 512 + w * 64 + l;
    const int row = f >> 2;
    const int ch = (f & 3) ^ ((row >> 1) & 3);  // pre-swizzled source chunk
    gload_lds16(g + (size_t)row * K + (ch << 3), gran + i * 4096 + w * 512);
  }
}

__global__ __launch_bounds__(512, 2) void gemm256_kernel(const f16_t* __restrict__ A,
                                                         const f16_t* __restrict__ Bt,
                                                         float* __restrict__ C,
                                                         const float* __restrict__ bias,
                                                         int M, int N, int K) {
  __shared__ __align__(16) f16_t lds[4 * 8192];  // 4 B-granules x 16 KB = 64 KB
  const int tid = threadIdx.x;
  const int l = tid & 63;
  const int w = tid >> 6;
  const int wr = w >> 2;
  const int wc = w & 3;
  const int lr = l & 15;
  const int q = l >> 4;

  const int cpx = (int)gridDim.x >> 3;
  const int swzb = ((int)blockIdx.x & 7) * cpx + ((int)blockIdx.x >> 3);
  const int nNT = N >> 8;
  const int mt = swzb / nNT;
  const int nt = swzb % nNT;
  const int m0 = mt << 8;
  const int n0 = nt << 8;

  const f16_t* Apanel = A + (size_t)m0 * K;
  const f16_t* Bpanel = Bt + (size_t)n0 * K;
  const f16_t* pA = Apanel + (size_t)((wr << 7) + lr) * K + (q << 3);  // lane A base
  const int sw = (q ^ ((lr >> 1) & 3)) << 3;  // B read swizzle (matches stageB)

  f32x4 acc[8][4];
#pragma unroll
  for (int m = 0; m < 8; ++m)
#pragma unroll
    for (int n = 0; n < 4; ++n) acc[m][n] = f32x4{0.f, 0.f, 0.f, 0.f};

  const int nK = K >> 5;  // 32 (even)

#define ALOAD(DST, KT)                                                  \
  do {                                                                  \
    const int kk_ = (KT) < nK ? (KT) : (nK - 1);                        \
    const f16_t* p_ = pA + ((size_t)kk_ << 5);                          \
    _Pragma("unroll") for (int m_ = 0; m_ < 8; ++m_)                    \
      DST[m_] = *(const f16x8*)(p_ + (size_t)(m_ << 4) * K);            \
  } while (0)

#define BREAD(BF, GRAN)                                                 \
  do {                                                                  \
    const f16_t* gB_ = lds + (size_t)(GRAN) * 8192;                     \
    _Pragma("unroll") for (int n_ = 0; n_ < 4; ++n_)                    \
      BF[n_] = *(const f16x8*)(gB_ + (((wc << 6) + (n_ << 4) + lr) << 5) + sw); \
  } while (0)

#define MFMAS(AF, BF)                                                   \
  do {                                                                  \
    __builtin_amdgcn_s_setprio(1);                                      \
    _Pragma("unroll") for (int m_ = 0; m_ < 8; ++m_)                    \
      _Pragma("unroll") for (int n_ = 0; n_ < 4; ++n_)                  \
        acc[m_][n_] = __builtin_amdgcn_mfma_f32_16x16x32_f16(           \
            AF[m_], BF[n_], acc[m_][n_], 0, 0, 0);                      \
    __builtin_amdgcn_s_setprio(0);                                      \
  } while (0)

#define STAGEB(TT)                                                      \
  do {                                                                  \
    const int ts_ = (TT) < nK ? (TT) : (nK - 1);                        \
    stageB(Bpanel + (ts_ << 5), K, lds + (ts_ & 3) * 8192, w, l);       \
  } while (0)

  f16x8 af0[8], af1[8];

  // prologue: B tiles 0,1 into granules 0,1; A(0) into af0; full drain once.
  stageB(Bpanel, K, lds, w, l);
  stageB(Bpanel + 32, K, lds + 8192, w, l);
  ALOAD(af0, 0);
  VMCNT(0);
  BARX();

  for (int t = 0; t < nK; t += 2) {
    // even step: consume af0 + B-granule t&3
    {
      f16x8 bf[4];
      BREAD(bf, t & 3);
      ALOAD(af1, t + 1);   // 8 vmem
      STAGEB(t + 2);       // 2 vmem
      MFMAS(af0, bf);
      VMCNT(2);            // A(t+1)+B(t+1) landed; B(t+2) flies
      BARX();
    }
    // odd step: consume af1 + B-granule (t+1)&3
    {
      f16x8 bf[4];
      BREAD(bf, (t + 1) & 3);
      ALOAD(af0, t + 2);   // clamped at tail (dead load, uniform count)
      STAGEB(t + 3);       // clamped at tail (identical-byte rewrite)
      MFMAS(af1, bf);
      VMCNT(2);
      BARX();
    }
  }
#undef ALOAD
#undef BREAD
#undef MFMAS
#undef STAGEB

  // epilogue: C/D layout col = l&15, row = (l>>4)*4 + j
  float bs[4];
#pragma unroll
  for (int n = 0; n < 4; ++n) bs[n] = bias[n0 + (wc << 6) + (n << 4) + lr];
#pragma unroll
  for (int m = 0; m < 8; ++m) {
    const int gm = m0 + (wr << 7) + (m << 4) + (q << 2);
#pragma unroll
    for (int j = 0; j < 4; ++j) {
      float* Crow = C + (size_t)(gm + j) * N + n0 + (wc << 6) + lr;
#pragma unroll
      for (int n = 0; n < 4; ++n) Crow[n << 4] = acc[m][n][j] + bs[n];
    }
  }
}

// ---------------- launch ----------------

extern "C" void kernel_launch(void* const* d_in, const int* in_sizes, int n_in,
                              void* d_out, int out_size, void* d_ws, size_t ws_size,
                              hipStream_t stream) {
  const float* x = (const float*)d_in[0];    // [8,4096,1024]
  const float* Wv = (const float*)d_in[1];   // [1024,1024]
  const float* bv = (const float*)d_in[2];   // [1024]
  const float* Wo = (const float*)d_in[3];   // [1024,1024]
  const float* bo = (const float*)d_in[4];   // [1024]
  const float* nw = (const float*)d_in[5];   // [3]
  float* out = (float*)d_out;

  char* ws = (char*)d_ws;
  f16_t* Wo_h = (f16_t*)(ws);                  // 2 MB
  f16_t* WvT  = (f16_t*)(ws + (2u << 20));     // 2 MB
  f16_t* WcT  = (f16_t*)(ws + (4u << 20));     // 2 MB (WcT = Wo @ Wv, [e][c])
  float* bc   = (float*)(ws + (6u << 20));     // 4 KB
  f16_t* Xavg = (f16_t*)(ws + (8u << 20));     // 64 MB

  prep_xavg_kernel<<<dim3(7168), dim3(256), 0, stream>>>(
      x, Wo, Wv, bv, bo, nw, in_sizes[5], Wo_h, WvT, bc, Xavg);
  gemm_bt_kernel<f16_t, false><<<dim3(64), dim3(256), 0, stream>>>(
      Wo_h, WvT, WcT, (const float*)nullptr, 1024, 1024, 1024);
  gemm256_kernel<<<dim3(512), dim3(512), 0, stream>>>(
      Xavg, WcT, out, bc, 32768, 1024, 1024);
}

// Round 10
// 147.743 us; speedup vs baseline: 1.5362x; 1.5362x over previous
//
#include <hip/hip_runtime.h>
#include <stdint.h>
#include <stddef.h>

typedef _Float16 f16_t;
typedef _Float16 f16x4 __attribute__((ext_vector_type(4)));
typedef _Float16 f16x8 __attribute__((ext_vector_type(8)));
typedef float f32x4 __attribute__((ext_vector_type(4)));

#define AS_G __attribute__((address_space(1)))
#define AS_L __attribute__((address_space(3)))

__device__ __forceinline__ void gload_lds16(const void* g, void* l) {
  __builtin_amdgcn_global_load_lds((AS_G void*)g, (AS_L void*)l, 16, 0, 0);
}

#define FENCE() asm volatile("" ::: "memory")
#define BARX()                            \
  do {                                    \
    FENCE();                              \
    __builtin_amdgcn_s_barrier();         \
    FENCE();                              \
  } while (0)
#define VMCNT(n) asm volatile("s_waitcnt vmcnt(" #n ")" ::: "memory")

// ---------------- merged prep + xavg kernel ----------------
// blocks [0,1024): Wo f32->f16 cvt; [1024,2048): Wv transpose+cvt;
// [2048,3072): bconst; [3072,7168): xavg 3-tap (8 rows/block)

__global__ __launch_bounds__(256) void prep_xavg_kernel(
    const float* __restrict__ X, const float* __restrict__ Wo,
    const float* __restrict__ Wv, const float* __restrict__ bv,
    const float* __restrict__ bo, const float* __restrict__ nw, int Kw,
    f16_t* __restrict__ Wo_h, f16_t* __restrict__ WvT, float* __restrict__ bc,
    f16_t* __restrict__ Xavg) {
  __shared__ float smem[32 * 33];
  const int b = blockIdx.x;
  const int t = threadIdx.x;
  if (b >= 3072) {
    const int T = 4096, D = 1024;
    const int base = (b - 3072) * 8;
    const int t0 = base & (T - 1);
    const int col = t * 4;
    const float w0 = nw[0], w1 = nw[1], w2 = nw[2];
    const float* xb = X + (size_t)base * D + col;
    f32x4 va = *(const f32x4*)(xb + (t0 == 0 ? 0 : -D));
    f32x4 vb = *(const f32x4*)(xb);
    f16_t* ob = Xavg + (size_t)base * D + col;
#pragma unroll
    for (int g = 0; g < 8; ++g) {
      f32x4 vc;
      if (t0 + g == T - 1) vc = vb;
      else vc = *(const f32x4*)(xb + (size_t)(g + 1) * D);
      f32x4 y = w0 * va + w1 * vb + w2 * vc;
      f16x4 o;
      o.x = (f16_t)y.x; o.y = (f16_t)y.y; o.z = (f16_t)y.z; o.w = (f16_t)y.w;
      *(f16x4*)(ob + (size_t)g * D) = o;
      va = vb;
      vb = vc;
    }
  } else if (b < 1024) {
    const int i = b * 256 + t;
    f32x4 v = ((const f32x4*)Wo)[i];
    f16x4 o;
    o.x = (f16_t)v.x; o.y = (f16_t)v.y; o.z = (f16_t)v.z; o.w = (f16_t)v.w;
    ((f16x4*)Wo_h)[i] = o;
  } else if (b < 2048) {
    const int i = b - 1024;
    const int bx = i & 31, by = i >> 5;
    const int tx = t & 31, ty = t >> 5;
#pragma unroll
    for (int k = 0; k < 32; k += 8)
      smem[(ty + k) * 33 + tx] = Wv[(size_t)(by * 32 + ty + k) * 1024 + bx * 32 + tx];
    __syncthreads();
#pragma unroll
    for (int k = 0; k < 32; k += 8)
      WvT[(size_t)(bx * 32 + ty + k) * 1024 + by * 32 + tx] = (f16_t)smem[tx * 33 + ty + k];
  } else {
    const int e = b - 2048;
    float sw = 0.f;
    for (int k = 0; k < Kw; ++k) sw += nw[k];
    float p = 0.f;
    for (int d = t; d < 1024; d += 256) p += Wo[(size_t)e * 1024 + d] * bv[d];
    smem[t] = p;
    __syncthreads();
    for (int s = 128; s > 0; s >>= 1) {
      if (t < s) smem[t] += smem[t + s];
      __syncthreads();
    }
    if (t == 0) bc[e] = sw * smem[0] + bo[e];
  }
}

// ---------------- 128^2 GEMM (small 1024^3 WcT GEMM) ----------------

template <typename OutT, bool BIAS>
__global__ __launch_bounds__(256) void gemm_bt_kernel(const f16_t* __restrict__ A,
                                                      const f16_t* __restrict__ Bt,
                                                      OutT* __restrict__ C,
                                                      const float* __restrict__ bias,
                                                      int M, int N, int K) {
  __shared__ __align__(16) f16_t sA[128 * 32];
  __shared__ __align__(16) f16_t sB[128 * 32];
  const int tid = threadIdx.x;
  const int l = tid & 63;
  const int w = tid >> 6;
  const int wr = w >> 1;
  const int wc = w & 1;
  const int nMT = M >> 7;
  const int bid = blockIdx.x;
  const int mt = bid % nMT;
  const int nt = bid / nMT;
  const int m0 = mt << 7;
  const int n0 = nt << 7;

  const int srow = (w << 4) + (l >> 2);
  const int scol = (l & 3) << 3;
  const size_t aoff0 = (size_t)(m0 + srow) * K + scol;
  const size_t boff0 = (size_t)(n0 + srow) * K + scol;
  f16_t* ldsA = sA + (w << 9);
  f16_t* ldsB = sB + (w << 9);

  f32x4 acc[4][4];
#pragma unroll
  for (int i = 0; i < 4; ++i)
#pragma unroll
    for (int j = 0; j < 4; ++j) acc[i][j] = f32x4{0.f, 0.f, 0.f, 0.f};

  const int ka = (l >> 4) << 3;
  const int ar = (wr << 6) + (l & 15);
  const int br = (wc << 6) + (l & 15);

  const int nK = K >> 5;
  for (int kt = 0; kt < nK; ++kt) {
    const int kb = kt << 5;
    gload_lds16(A + aoff0 + kb, ldsA);
    gload_lds16(A + aoff0 + ((size_t)K << 6) + kb, ldsA + 2048);
    gload_lds16(Bt + boff0 + kb, ldsB);
    gload_lds16(Bt + boff0 + ((size_t)K << 6) + kb, ldsB + 2048);
    __syncthreads();
    f16x8 af[4], bfr[4];
#pragma unroll
    for (int m = 0; m < 4; ++m) af[m] = *(const f16x8*)(sA + ((ar + (m << 4)) << 5) + ka);
#pragma unroll
    for (int n = 0; n < 4; ++n) bfr[n] = *(const f16x8*)(sB + ((br + (n << 4)) << 5) + ka);
#pragma unroll
    for (int m = 0; m < 4; ++m)
#pragma unroll
      for (int n = 0; n < 4; ++n)
        acc[m][n] = __builtin_amdgcn_mfma_f32_16x16x32_f16(af[m], bfr[n], acc[m][n], 0, 0, 0);
    __syncthreads();
  }

  const int orow = (l >> 4) << 2;
  const int ocol = l & 15;
#pragma unroll
  for (int n = 0; n < 4; ++n) {
    const int gn = n0 + (wc << 6) + (n << 4) + ocol;
    const float bs = BIAS ? bias[gn] : 0.f;
#pragma unroll
    for (int m = 0; m < 4; ++m) {
      const int gm = m0 + (wr << 6) + (m << 4) + orow;
#pragma unroll
      for (int j = 0; j < 4; ++j) {
        C[(size_t)(gm + j) * N + gn] = (OutT)(acc[m][n][j] + bs);
      }
    }
  }
}

// ---------------- GEMM v8: 256x128 tile, 2 blocks/CU, ring-3, counted vmcnt ----------------
// C[M][N] = A[M][K]*Bt[N][K]^T + bias. 512 thr / 8 waves (2M x 4N), wave tile 128x32,
// BK=32, 16x16x32 MFMA. acc = 64 VGPR/thread -> ~120 total, __launch_bounds__(512,4)
// => 4 waves/SIMD. LDS: 3 granules x (A 256x32 + B 128x32 f16 = 24 KB) = 72 KB
// => 2 blocks/CU. Cross-block TLP is the latency-hiding engine (m114).
// Schedule per step t: issue stage(t+2) (3 gloads) into granule (t+2)%3; ds_read
// 10 frags from granule t%3; 16 MFMA; VMCNT(3) (tile t+1 certified, t+2 in flight);
// barrier. Granule (t+2)%3 was last read at step t-1, whose readers all passed the
// end-of-(t-1) barrier before these gloads issue. Tails clamped (dup-byte rewrites
// into dead granules; uniform vmem counts).
// XOR chunk swizzle ch ^= (row>>1)&3 on gload SOURCE and ds_read (involution, 0-conflict).

__device__ __forceinline__ void stageOp(const f16_t* __restrict__ g, int K, int rows2,
                                        f16_t* gran, int w, int l) {
  // rows2 = rows/... iterations: rows*32 f16 / (512 thr * 8 f16) ; A: 2, B: 1
#pragma unroll
  for (int i = 0; i < 2; ++i) {
    if (i >= rows2) break;
    const int f = i * 512 + w * 64 + l;
    const int row = f >> 2;
    const int ch = (f & 3) ^ ((row >> 1) & 3);
    gload_lds16(g + (size_t)row * K + (ch << 3), gran + i * 4096 + w * 512);
  }
}

__global__ __launch_bounds__(512, 4) void gemm_hi_kernel(const f16_t* __restrict__ A,
                                                         const f16_t* __restrict__ Bt,
                                                         float* __restrict__ C,
                                                         const float* __restrict__ bias,
                                                         int M, int N, int K) {
  __shared__ __align__(16) f16_t lds[3 * 12288];  // 3 x 24 KB = 72 KB
  const int tid = threadIdx.x;
  const int l = tid & 63;
  const int w = tid >> 6;
  const int wr = w >> 2;   // 0..1 -> 128-row half
  const int wc = w & 3;    // 0..3 -> 32-col slice
  const int lr = l & 15;
  const int q = l >> 4;

  // XCD swizzle; same-mt blocks (8 nt) land on one XCD for A-panel L2 reuse
  const int cpx = (int)gridDim.x >> 3;  // 128
  const int swzb = ((int)blockIdx.x & 7) * cpx + ((int)blockIdx.x >> 3);
  const int nNT = N >> 7;  // 8
  const int mt = swzb / nNT;
  const int nt = swzb % nNT;
  const int m0 = mt << 8;
  const int n0 = nt << 7;

  const f16_t* Apanel = A + (size_t)m0 * K;
  const f16_t* Bpanel = Bt + (size_t)n0 * K;
  const int sw = (q ^ ((lr >> 1) & 3)) << 3;

  f32x4 acc[8][2];
#pragma unroll
  for (int m = 0; m < 8; ++m)
#pragma unroll
    for (int n = 0; n < 2; ++n) acc[m][n] = f32x4{0.f, 0.f, 0.f, 0.f};

  const int nK = K >> 5;  // 32

#define STAGE(TT, GI)                                                       \
  do {                                                                      \
    const int ts_ = (TT) < nK ? (TT) : (nK - 1);                            \
    f16_t* g_ = lds + (GI) * 12288;                                         \
    stageOp(Apanel + (ts_ << 5), K, 2, g_, w, l);                           \
    stageOp(Bpanel + (ts_ << 5), K, 1, g_ + 8192, w, l);                    \
  } while (0)

  // prologue: tiles 0,1 into granules 0,1 (6 vmem/wave)
  STAGE(0, 0);
  STAGE(1, 1);
  VMCNT(3);  // tile 0 landed (tile 1's 3 fly)
  BARX();

  int cur = 0, stg = 2;
  for (int t = 0; t < nK; ++t) {
    STAGE(t + 2, stg);  // 3 vmem -> outstanding 6

    const f16_t* gA = lds + cur * 12288;
    const f16_t* gB = gA + 8192;
    f16x8 af[8], bf[2];
#pragma unroll
    for (int n = 0; n < 2; ++n)
      bf[n] = *(const f16x8*)(gB + (((wc << 5) + (n << 4) + lr) << 5) + sw);
#pragma unroll
    for (int m = 0; m < 8; ++m)
      af[m] = *(const f16x8*)(gA + (((wr << 7) + (m << 4) + lr) << 5) + sw);

    __builtin_amdgcn_s_setprio(1);
#pragma unroll
    for (int m = 0; m < 8; ++m)
#pragma unroll
      for (int n = 0; n < 2; ++n)
        acc[m][n] = __builtin_amdgcn_mfma_f32_16x16x32_f16(af[m], bf[n], acc[m][n], 0, 0, 0);
    __builtin_amdgcn_s_setprio(0);

    VMCNT(3);  // tile t+1 fully landed; tile t+2 (3 instrs) still flying
    BARX();
    cur = (cur == 2) ? 0 : cur + 1;
    stg = (stg == 2) ? 0 : stg + 1;
  }
#undef STAGE

  // epilogue: C/D layout col = l&15, row = (l>>4)*4 + j
  float bs[2];
#pragma unroll
  for (int n = 0; n < 2; ++n) bs[n] = bias[n0 + (wc << 5) + (n << 4) + lr];
#pragma unroll
  for (int m = 0; m < 8; ++m) {
    const int gm = m0 + (wr << 7) + (m << 4) + (q << 2);
#pragma unroll
    for (int j = 0; j < 4; ++j) {
      float* Crow = C + (size_t)(gm + j) * N + n0 + (wc << 5) + lr;
#pragma unroll
      for (int n = 0; n < 2; ++n) Crow[n << 4] = acc[m][n][j] + bs[n];
    }
  }
}

// ---------------- launch ----------------

extern "C" void kernel_launch(void* const* d_in, const int* in_sizes, int n_in,
                              void* d_out, int out_size, void* d_ws, size_t ws_size,
                              hipStream_t stream) {
  const float* x = (const float*)d_in[0];    // [8,4096,1024]
  const float* Wv = (const float*)d_in[1];   // [1024,1024]
  const float* bv = (const float*)d_in[2];   // [1024]
  const float* Wo = (const float*)d_in[3];   // [1024,1024]
  const float* bo = (const float*)d_in[4];   // [1024]
  const float* nw = (const float*)d_in[5];   // [3]
  float* out = (float*)d_out;

  char* ws = (char*)d_ws;
  f16_t* Wo_h = (f16_t*)(ws);                  // 2 MB
  f16_t* WvT  = (f16_t*)(ws + (2u << 20));     // 2 MB
  f16_t* WcT  = (f16_t*)(ws + (4u << 20));     // 2 MB (WcT = Wo @ Wv, [e][c])
  float* bc   = (float*)(ws + (6u << 20));     // 4 KB
  f16_t* Xavg = (f16_t*)(ws + (8u << 20));     // 64 MB

  prep_xavg_kernel<<<dim3(7168), dim3(256), 0, stream>>>(
      x, Wo, Wv, bv, bo, nw, in_sizes[5], Wo_h, WvT, bc, Xavg);
  gemm_bt_kernel<f16_t, false><<<dim3(64), dim3(256), 0, stream>>>(
      Wo_h, WvT, WcT, (const float*)nullptr, 1024, 1024, 1024);
  // out[r][e] = sum_c Xavg[r][c] * WcT[e][c] + bc[e]  (256x128 tiles, 1024 blocks)
  gemm_hi_kernel<<<dim3(1024), dim3(512), 0, stream>>>(
      Xavg, WcT, out, bc, 32768, 1024, 1024);
}

// Round 11
// 145.058 us; speedup vs baseline: 1.5647x; 1.0185x over previous
//
#include <hip/hip_runtime.h>
#include <stdint.h>
#include <stddef.h>

typedef _Float16 f16_t;
typedef _Float16 f16x4 __attribute__((ext_vector_type(4)));
typedef _Float16 f16x8 __attribute__((ext_vector_type(8)));
typedef float f32x4 __attribute__((ext_vector_type(4)));

#define AS_G __attribute__((address_space(1)))
#define AS_L __attribute__((address_space(3)))

__device__ __forceinline__ void gload_lds16(const void* g, void* l) {
  __builtin_amdgcn_global_load_lds((AS_G void*)g, (AS_L void*)l, 16, 0, 0);
}

#define FENCE() asm volatile("" ::: "memory")
#define BARX()                            \
  do {                                    \
    FENCE();                              \
    __builtin_amdgcn_s_barrier();         \
    FENCE();                              \
  } while (0)
#define VMCNT(n) asm volatile("s_waitcnt vmcnt(" #n ")" ::: "memory")

// ---------------- dispatch 1: weight prep ----------------
// blocks [0,1024): Wo f32->f16 cvt; [1024,2048): Wv transpose+cvt; [2048,3072): bconst

__global__ __launch_bounds__(256) void prep_w_kernel(
    const float* __restrict__ Wo, const float* __restrict__ Wv,
    const float* __restrict__ bv, const float* __restrict__ bo,
    const float* __restrict__ nw, int Kw,
    f16_t* __restrict__ Wo_h, f16_t* __restrict__ WvT, float* __restrict__ bc) {
  __shared__ float smem[32 * 33];
  const int b = blockIdx.x;
  const int t = threadIdx.x;
  if (b < 1024) {
    const int i = b * 256 + t;
    f32x4 v = ((const f32x4*)Wo)[i];
    f16x4 o;
    o.x = (f16_t)v.x; o.y = (f16_t)v.y; o.z = (f16_t)v.z; o.w = (f16_t)v.w;
    ((f16x4*)Wo_h)[i] = o;
  } else if (b < 2048) {
    const int i = b - 1024;
    const int bx = i & 31, by = i >> 5;
    const int tx = t & 31, ty = t >> 5;
#pragma unroll
    for (int k = 0; k < 32; k += 8)
      smem[(ty + k) * 33 + tx] = Wv[(size_t)(by * 32 + ty + k) * 1024 + bx * 32 + tx];
    __syncthreads();
#pragma unroll
    for (int k = 0; k < 32; k += 8)
      WvT[(size_t)(bx * 32 + ty + k) * 1024 + by * 32 + tx] = (f16_t)smem[tx * 33 + ty + k];
  } else {
    const int e = b - 2048;
    float sw = 0.f;
    for (int k = 0; k < Kw; ++k) sw += nw[k];
    float p = 0.f;
    for (int d = t; d < 1024; d += 256) p += Wo[(size_t)e * 1024 + d] * bv[d];
    smem[t] = p;
    __syncthreads();
    for (int s = 128; s > 0; s >>= 1) {
      if (t < s) smem[t] += smem[t + s];
      __syncthreads();
    }
    if (t == 0) bc[e] = sw * smem[0] + bo[e];
  }
}

// ---------------- dispatch 2: xavg (memory-bound) || WcT GEMM (compute) ----------------
// blocks [0,4096): xavg 3-tap, 8 rows/block; [4096,4160): 128^2 GEMM WcT = Wo_h @ WvT^T.
// The 64 GEMM blocks co-run on CUs while the rest stream xavg -> GEMM time hidden.

__global__ __launch_bounds__(256) void xavg_wct_kernel(
    const float* __restrict__ X, const float* __restrict__ nw,
    const f16_t* __restrict__ Wo_h, const f16_t* __restrict__ WvT,
    f16_t* __restrict__ Xavg, f16_t* __restrict__ WcT) {
  __shared__ __align__(16) f16_t smem[2 * 128 * 32];  // 16 KB (GEMM branch only)
  const int b = blockIdx.x;
  const int tid = threadIdx.x;

  if (b < 4096) {
    // ---- xavg: 3-tap temporal smoothing, fp16 out ----
    const int T = 4096, D = 1024;
    const int base = b * 8;
    const int t0 = base & (T - 1);
    const int col = tid * 4;
    const float w0 = nw[0], w1 = nw[1], w2 = nw[2];
    const float* xb = X + (size_t)base * D + col;
    f32x4 va = *(const f32x4*)(xb + (t0 == 0 ? 0 : -D));
    f32x4 vb = *(const f32x4*)(xb);
    f16_t* ob = Xavg + (size_t)base * D + col;
#pragma unroll
    for (int g = 0; g < 8; ++g) {
      f32x4 vc;
      if (t0 + g == T - 1) vc = vb;
      else vc = *(const f32x4*)(xb + (size_t)(g + 1) * D);
      f32x4 y = w0 * va + w1 * vb + w2 * vc;
      f16x4 o;
      o.x = (f16_t)y.x; o.y = (f16_t)y.y; o.z = (f16_t)y.z; o.w = (f16_t)y.w;
      *(f16x4*)(ob + (size_t)g * D) = o;
      va = vb;
      vb = vc;
    }
    return;
  }

  // ---- 128^2 MFMA GEMM: WcT[e][c] = sum_d Wo_h[e][d] * WvT[c][d] (M=N=K=1024) ----
  constexpr int K = 1024, N = 1024;
  f16_t* sA = smem;
  f16_t* sB = smem + 128 * 32;
  const int l = tid & 63;
  const int w = tid >> 6;
  const int wr = w >> 1;
  const int wc = w & 1;
  const int bid = b - 4096;
  const int mt = bid & 7;
  const int nt = bid >> 3;
  const int m0 = mt << 7;
  const int n0 = nt << 7;

  const int srow = (w << 4) + (l >> 2);
  const int scol = (l & 3) << 3;
  const size_t aoff0 = (size_t)(m0 + srow) * K + scol;
  const size_t boff0 = (size_t)(n0 + srow) * K + scol;
  f16_t* ldsA = sA + (w << 9);
  f16_t* ldsB = sB + (w << 9);

  f32x4 acc[4][4];
#pragma unroll
  for (int i = 0; i < 4; ++i)
#pragma unroll
    for (int j = 0; j < 4; ++j) acc[i][j] = f32x4{0.f, 0.f, 0.f, 0.f};

  const int ka = (l >> 4) << 3;
  const int ar = (wr << 6) + (l & 15);
  const int br = (wc << 6) + (l & 15);

  for (int kt = 0; kt < (K >> 5); ++kt) {
    const int kb = kt << 5;
    gload_lds16(Wo_h + aoff0 + kb, ldsA);
    gload_lds16(Wo_h + aoff0 + ((size_t)K << 6) + kb, ldsA + 2048);
    gload_lds16(WvT + boff0 + kb, ldsB);
    gload_lds16(WvT + boff0 + ((size_t)K << 6) + kb, ldsB + 2048);
    __syncthreads();
    f16x8 af[4], bfr[4];
#pragma unroll
    for (int m = 0; m < 4; ++m) af[m] = *(const f16x8*)(sA + ((ar + (m << 4)) << 5) + ka);
#pragma unroll
    for (int n = 0; n < 4; ++n) bfr[n] = *(const f16x8*)(sB + ((br + (n << 4)) << 5) + ka);
#pragma unroll
    for (int m = 0; m < 4; ++m)
#pragma unroll
      for (int n = 0; n < 4; ++n)
        acc[m][n] = __builtin_amdgcn_mfma_f32_16x16x32_f16(af[m], bfr[n], acc[m][n], 0, 0, 0);
    __syncthreads();
  }

  const int orow = (l >> 4) << 2;
  const int ocol = l & 15;
#pragma unroll
  for (int n = 0; n < 4; ++n) {
    const int gn = n0 + (wc << 6) + (n << 4) + ocol;
#pragma unroll
    for (int m = 0; m < 4; ++m) {
      const int gm = m0 + (wr << 6) + (m << 4) + orow;
#pragma unroll
      for (int j = 0; j < 4; ++j) {
        WcT[(size_t)(gm + j) * N + gn] = (f16_t)acc[m][n][j];
      }
    }
  }
}

// ---------------- dispatch 3: 256^2 pipelined GEMM (round-5 best: ring-4, 1 bar, vmcnt(8)) ----------------
// out[M][N] = Xavg[M][K]*WcT[N][K]^T + bc. 8 waves (2Mx4N), BK=32, 16x16x32 MFMA.
// Ring-4 LDS granules (32 KB each = 128 KB), prefetch distance 3, one counted
// VMCNT(8) + one barrier per K-step. XOR chunk swizzle both sides (0-conflict).
// Tails clamped (identical-byte rewrites, uniform vmem counts).

__device__ __forceinline__ void stage256(const f16_t* __restrict__ g, int K,
                                         f16_t* ldsOp, int w, int l) {
#pragma unroll
  for (int i = 0; i < 2; ++i) {
    const int f = i * 512 + w * 64 + l;
    const int row = f >> 2;
    const int ch = f & 3;
    const int col = (((ch ^ ((row >> 1) & 3))) << 3);
    gload_lds16(g + (size_t)row * K + col, ldsOp + i * 4096 + w * 512);
  }
}

__global__ __launch_bounds__(512, 2) void gemm256_kernel(const f16_t* __restrict__ A,
                                                         const f16_t* __restrict__ Bt,
                                                         float* __restrict__ C,
                                                         const float* __restrict__ bias,
                                                         int M, int N, int K) {
  __shared__ __align__(16) f16_t lds[4 * 16384];
  const int tid = threadIdx.x;
  const int l = tid & 63;
  const int w = tid >> 6;
  const int wr = w >> 2;
  const int wc = w & 3;
  const int lr = l & 15;
  const int q = l >> 4;

  const int cpx = (int)gridDim.x >> 3;
  const int swzb = ((int)blockIdx.x & 7) * cpx + ((int)blockIdx.x >> 3);
  const int nNT = N >> 8;
  const int mt = swzb / nNT;
  const int nt = swzb % nNT;
  const int m0 = mt << 8;
  const int n0 = nt << 8;

  const f16_t* Apanel = A + (size_t)m0 * K;
  const f16_t* Bpanel = Bt + (size_t)n0 * K;
  const int sw = (q ^ ((lr >> 1) & 3)) << 3;

  f32x4 acc[8][4];
#pragma unroll
  for (int m = 0; m < 8; ++m)
#pragma unroll
    for (int n = 0; n < 4; ++n) acc[m][n] = f32x4{0.f, 0.f, 0.f, 0.f};

  const int nK = K >> 5;

  for (int t = 0; t < 3; ++t) {
    f16_t* buf = lds + (t & 3) * 16384;
    stage256(Apanel + (t << 5), K, buf, w, l);
    stage256(Bpanel + (t << 5), K, buf + 8192, w, l);
  }
  VMCNT(8);
  BARX();

  for (int t = 0; t < nK; ++t) {
    f16_t* sA = lds + (t & 3) * 16384;
    f16_t* sB = sA + 8192;

    {
      const int tn = (t + 3) < nK ? (t + 3) : (nK - 1);
      f16_t* nbuf = lds + ((t + 3) & 3) * 16384;
      stage256(Apanel + ((size_t)tn << 5), K, nbuf, w, l);
      stage256(Bpanel + ((size_t)tn << 5), K, nbuf + 8192, w, l);
    }

    f16x8 bf[4], af[4], ag[4];
#pragma unroll
    for (int n = 0; n < 4; ++n)
      bf[n] = *(const f16x8*)(sB + (((wc << 6) + (n << 4) + lr) << 5) + sw);
#pragma unroll
    for (int m = 0; m < 4; ++m)
      af[m] = *(const f16x8*)(sA + (((wr << 7) + (m << 4) + lr) << 5) + sw);
#pragma unroll
    for (int m = 0; m < 4; ++m)
      ag[m] = *(const f16x8*)(sA + (((wr << 7) + 64 + (m << 4) + lr) << 5) + sw);

    __builtin_amdgcn_s_setprio(1);
#pragma unroll
    for (int m = 0; m < 4; ++m)
#pragma unroll
      for (int n = 0; n < 4; ++n)
        acc[m][n] = __builtin_amdgcn_mfma_f32_16x16x32_f16(af[m], bf[n], acc[m][n], 0, 0, 0);
#pragma unroll
    for (int m = 0; m < 4; ++m)
#pragma unroll
      for (int n = 0; n < 4; ++n)
        acc[m + 4][n] = __builtin_amdgcn_mfma_f32_16x16x32_f16(ag[m], bf[n], acc[m + 4][n], 0, 0, 0);
    __builtin_amdgcn_s_setprio(0);

    VMCNT(8);
    BARX();
  }

  float bs[4];
#pragma unroll
  for (int n = 0; n < 4; ++n) bs[n] = bias[n0 + (wc << 6) + (n << 4) + lr];
#pragma unroll
  for (int m = 0; m < 8; ++m) {
    const int gm = m0 + (wr << 7) + (m << 4) + (q << 2);
#pragma unroll
    for (int j = 0; j < 4; ++j) {
      float* Crow = C + (size_t)(gm + j) * N + n0 + (wc << 6) + lr;
#pragma unroll
      for (int n = 0; n < 4; ++n) Crow[n << 4] = acc[m][n][j] + bs[n];
    }
  }
}

// ---------------- launch ----------------

extern "C" void kernel_launch(void* const* d_in, const int* in_sizes, int n_in,
                              void* d_out, int out_size, void* d_ws, size_t ws_size,
                              hipStream_t stream) {
  const float* x = (const float*)d_in[0];    // [8,4096,1024]
  const float* Wv = (const float*)d_in[1];   // [1024,1024]
  const float* bv = (const float*)d_in[2];   // [1024]
  const float* Wo = (const float*)d_in[3];   // [1024,1024]
  const float* bo = (const float*)d_in[4];   // [1024]
  const float* nw = (const float*)d_in[5];   // [3]
  float* out = (float*)d_out;

  char* ws = (char*)d_ws;
  f16_t* Wo_h = (f16_t*)(ws);                  // 2 MB
  f16_t* WvT  = (f16_t*)(ws + (2u << 20));     // 2 MB
  f16_t* WcT  = (f16_t*)(ws + (4u << 20));     // 2 MB (WcT = Wo @ Wv, [e][c])
  float* bc   = (float*)(ws + (6u << 20));     // 4 KB
  f16_t* Xavg = (f16_t*)(ws + (8u << 20));     // 64 MB

  // 1) weight prep: cvt + transpose + bconst (fast, small)
  prep_w_kernel<<<dim3(3072), dim3(256), 0, stream>>>(
      Wo, Wv, bv, bo, nw, in_sizes[5], Wo_h, WvT, bc);
  // 2) xavg (memory-bound) co-running with WcT GEMM (compute-bound, 64 blocks)
  xavg_wct_kernel<<<dim3(4160), dim3(256), 0, stream>>>(
      x, nw, Wo_h, WvT, Xavg, WcT);
  // 3) out[r][e] = sum_c Xavg[r][c] * WcT[e][c] + bc[e]
  gemm256_kernel<<<dim3(512), dim3(512), 0, stream>>>(
      Xavg, WcT, out, bc, 32768, 1024, 1024);
}